// Round 1
// baseline (412.304 us; speedup 1.0000x reference)
//
#include <hip/hip_runtime.h>

#define LN 4096
#define DN 150
#define NPAD 160   // D padded to 10 x 16 MFMA n-tiles
#define NT 10

typedef __attribute__((ext_vector_type(8))) short bf16x8;
typedef __attribute__((ext_vector_type(4))) float f32x4;
typedef __attribute__((ext_vector_type(2))) float f32x2;

// round-to-nearest-even fp32 -> bf16 (finite inputs only)
__device__ __forceinline__ short f2bf(float f) {
    unsigned int u = __builtin_bit_cast(unsigned int, f);
    u = (u + 0x7FFFu + ((u >> 16) & 1u)) >> 16;
    return (short)u;
}

// h [4096][150] f32  ->  Ht [160][4096] bf16 (rows 150..159 zero)
__global__ __launch_bounds__(256) void k_transpose(const float* __restrict__ h,
                                                   unsigned short* __restrict__ Ht) {
    __shared__ float S[64][33];
    const int i0 = blockIdx.x * 64;
    const int d0 = blockIdx.y * 32;
    const int tid = threadIdx.x;
    for (int t = tid; t < 64 * 32; t += 256) {
        int ii = t >> 5, dd = t & 31;
        int d = d0 + dd;
        S[ii][dd] = (d < DN) ? h[(size_t)(i0 + ii) * DN + d] : 0.0f;
    }
    __syncthreads();
    for (int t = tid; t < 32 * 64; t += 256) {
        int dd = t >> 6, ii = t & 63;
        Ht[(size_t)(d0 + dd) * LN + i0 + ii] = (unsigned short)f2bf(S[ii][dd]);
    }
}

// TRANS==0: out[m0+r][d] = sum_k (adj[m0+r][k][0]+adj[m0+r][k][1]) * h[k][d]   (h_out)
// TRANS==1: out[m0+r][d] = sum_k (adj[k][m0+r][0]+adj[k][m0+r][1]) * h[k][d]   (h_in)
template <int TRANS>
__global__ __launch_bounds__(256) void k_gemm(const float* __restrict__ adj,
                                              const unsigned short* __restrict__ Ht,
                                              float* __restrict__ out) {
    const int tid  = threadIdx.x;
    const int lane = tid & 63;
    const int wave = tid >> 6;
    const int r = lane & 15;   // A row / B col / C col within 16-tile
    const int g = lane >> 4;   // k-group
    const int m0 = blockIdx.x * 16;
    const int kbeg = wave * (LN / 4);   // waves split K into quarters

    const f32x4 zero = {0.f, 0.f, 0.f, 0.f};
    f32x4 acc[NT];
    #pragma unroll
    for (int t = 0; t < NT; ++t) acc[t] = zero;

    f32x4 abuf[2][4];    // TRANS==0 raw adj (16 floats = 8 (e0,e1) pairs along k)
    f32x2 abuf2[2][8];   // TRANS==1 raw adj (8 strided (e0,e1) pairs along k=i)
    bf16x8 bbuf[2][NT];

    const f32x4* adj4 = reinterpret_cast<const f32x4*>(adj);
    const f32x2* adj2 = reinterpret_cast<const f32x2*>(adj);
    const size_t arow = (size_t)(m0 + r) * LN;

    auto loadA = [&](int slot, int s) {
        int k = kbeg + s * 32 + g * 8;
        if (TRANS == 0) {
            const f32x4* p = adj4 + ((arow + (size_t)k) >> 1);
            #pragma unroll
            for (int q = 0; q < 4; ++q) abuf[slot][q] = p[q];
        } else {
            #pragma unroll
            for (int q = 0; q < 8; ++q)
                abuf2[slot][q] = adj2[(size_t)(k + q) * LN + m0 + r];
        }
    };
    auto loadB = [&](int slot, int s) {
        int k = kbeg + s * 32 + g * 8;
        #pragma unroll
        for (int t = 0; t < NT; ++t)
            bbuf[slot][t] = *reinterpret_cast<const bf16x8*>(Ht + (size_t)(t * 16 + r) * LN + k);
    };
    auto proc = [&](int slot) {
        bf16x8 a;
        if (TRANS == 0) {
            #pragma unroll
            for (int q = 0; q < 4; ++q) {
                f32x4 v = abuf[slot][q];
                a[2 * q]     = f2bf(v.x + v.y);
                a[2 * q + 1] = f2bf(v.z + v.w);
            }
        } else {
            #pragma unroll
            for (int q = 0; q < 8; ++q) {
                f32x2 v = abuf2[slot][q];
                a[q] = f2bf(v.x + v.y);
            }
        }
        #pragma unroll
        for (int t = 0; t < NT; ++t)
            acc[t] = __builtin_amdgcn_mfma_f32_16x16x32_bf16(a, bbuf[slot][t], acc[t], 0, 0, 0);
    };

    // register-double-buffered K pipeline: A depth-2 (HBM), B depth-1 (L2)
    loadA(0, 0);
    loadB(0, 0);
    loadA(1, 1);
    for (int s = 0; s < 32; ++s) {
        const int slot = s & 1;
        if (s + 1 < 32) loadB(slot ^ 1, s + 1);
        proc(slot);
        if (s + 2 < 32) loadA(slot, s + 2);
    }

    // cross-wave K reduction in LDS, then store
    __shared__ float buf[16 * NPAD];
    const int row4 = g * 4;
    for (int w4 = 0; w4 < 4; ++w4) {
        if (wave == w4) {
            #pragma unroll
            for (int t = 0; t < NT; ++t) {
                #pragma unroll
                for (int q = 0; q < 4; ++q) {
                    int idx = (row4 + q) * NPAD + t * 16 + r;  // C: col=lane&15, row=(lane>>4)*4+q
                    if (w4 == 0) buf[idx] = acc[t][q];
                    else         buf[idx] += acc[t][q];
                }
            }
        }
        __syncthreads();
    }
    for (int t2 = tid; t2 < 16 * DN; t2 += 256) {
        int row = t2 / DN, col = t2 % DN;
        out[(size_t)(m0 + row) * DN + col] = buf[row * NPAD + col];
    }
}

extern "C" void kernel_launch(void* const* d_in, const int* in_sizes, int n_in,
                              void* d_out, int out_size, void* d_ws, size_t ws_size,
                              hipStream_t stream) {
    const float* adj = (const float*)d_in[0];
    const float* h   = (const float*)d_in[1];
    float* out = (float*)d_out;
    unsigned short* Ht = (unsigned short*)d_ws;  // 160*4096*2 = 1.31 MB scratch

    k_transpose<<<dim3(64, 5), 256, 0, stream>>>(h, Ht);
    // d_out layout: [h_in (L*D) | h_out (L*D)]
    k_gemm<0><<<256, 256, 0, stream>>>(adj, Ht, out + (size_t)LN * DN); // h_out = A  @ h
    k_gemm<1><<<256, 256, 0, stream>>>(adj, Ht, out);                   // h_in  = A.T@ h
}

// Round 3
// 110.404 us; speedup vs baseline: 3.7345x; 3.7345x over previous
//
#include <hip/hip_runtime.h>

#define LN 4096
#define DN 150
#define NPAD 160   // D padded to 10 x 16 MFMA n-tiles
#define NT 10

typedef __attribute__((ext_vector_type(8))) short bf16x8;
typedef __attribute__((ext_vector_type(4))) float f32x4;
typedef __attribute__((ext_vector_type(2))) float f32x2;

// round-to-nearest-even fp32 -> bf16 (finite inputs only)
__device__ __forceinline__ short f2bf(float f) {
    unsigned int u = __builtin_bit_cast(unsigned int, f);
    u = (u + 0x7FFFu + ((u >> 16) & 1u)) >> 16;
    return (short)u;
}

// h [4096][150] f32  ->  Ht [160][4096] bf16 (rows 150..159 zero)
__global__ __launch_bounds__(256) void k_transpose(const float* __restrict__ h,
                                                   unsigned short* __restrict__ Ht) {
    __shared__ float S[64][33];
    const int i0 = blockIdx.x * 64;
    const int d0 = blockIdx.y * 32;
    const int tid = threadIdx.x;
    for (int t = tid; t < 64 * 32; t += 256) {
        int ii = t >> 5, dd = t & 31;
        int d = d0 + dd;
        S[ii][dd] = (d < DN) ? h[(size_t)(i0 + ii) * DN + d] : 0.0f;
    }
    __syncthreads();
    for (int t = tid; t < 32 * 64; t += 256) {
        int dd = t >> 6, ii = t & 63;
        Ht[(size_t)(d0 + dd) * LN + i0 + ii] = (unsigned short)f2bf(S[ii][dd]);
    }
}

// TRANS==0: out[m0+r][d] = sum_k (adj[m0+r][k][0]+adj[m0+r][k][1]) * h[k][d]   (h_out)
// TRANS==1: out[m0+r][d] = sum_k (adj[k][m0+r][0]+adj[k][m0+r][1]) * h[k][d]   (h_in)
template <int TRANS>
__global__ __launch_bounds__(256) void k_gemm(const float* __restrict__ adj,
                                              const unsigned short* __restrict__ Ht,
                                              float* __restrict__ out) {
    const int tid  = threadIdx.x;
    const int lane = tid & 63;
    const int wave = tid >> 6;
    const int r = lane & 15;   // A row / B col / C col within 16-tile
    const int g = lane >> 4;   // k-group
    const int m0 = blockIdx.x * 16;
    const int kbeg = wave * (LN / 4);   // waves split K into quarters

    const f32x4 zero = {0.f, 0.f, 0.f, 0.f};
    f32x4 acc[NT];
    #pragma unroll
    for (int t = 0; t < NT; ++t) acc[t] = zero;

    // named (statically-indexed) pipeline buffers — rule #20: no runtime slot index
    f32x4 Aa[4], Ab[4];       // TRANS==0 raw adj (16 floats = 8 (e0,e1) pairs along k)
    f32x2 Aa2[8], Ab2[8];     // TRANS==1 raw adj (8 strided (e0,e1) pairs along k=i)
    bf16x8 Ba[NT], Bb[NT];

    const f32x4* adj4 = reinterpret_cast<const f32x4*>(adj);
    const f32x2* adj2 = reinterpret_cast<const f32x2*>(adj);
    const size_t arow = (size_t)(m0 + r) * LN;

    auto loadA0 = [&](f32x4 (&ab)[4], int s) {
        int k = kbeg + s * 32 + g * 8;
        const f32x4* p = adj4 + ((arow + (size_t)k) >> 1);
        #pragma unroll
        for (int q = 0; q < 4; ++q) ab[q] = p[q];
    };
    auto loadA1 = [&](f32x2 (&ab)[8], int s) {
        int k = kbeg + s * 32 + g * 8;
        #pragma unroll
        for (int q = 0; q < 8; ++q)
            ab[q] = adj2[(size_t)(k + q) * LN + m0 + r];
    };
    auto loadB = [&](bf16x8 (&bb)[NT], int s) {
        int k = kbeg + s * 32 + g * 8;
        #pragma unroll
        for (int t = 0; t < NT; ++t)
            bb[t] = *reinterpret_cast<const bf16x8*>(Ht + (size_t)(t * 16 + r) * LN + k);
    };
    auto proc = [&](f32x4 (&ab)[4], f32x2 (&ab2)[8], bf16x8 (&bb)[NT]) {
        bf16x8 a;
        if (TRANS == 0) {
            #pragma unroll
            for (int q = 0; q < 4; ++q) {
                f32x4 v = ab[q];
                a[2 * q]     = f2bf(v.x + v.y);
                a[2 * q + 1] = f2bf(v.z + v.w);
            }
        } else {
            #pragma unroll
            for (int q = 0; q < 8; ++q) {
                f32x2 v = ab2[q];
                a[q] = f2bf(v.x + v.y);
            }
        }
        #pragma unroll
        for (int t = 0; t < NT; ++t)
            acc[t] = __builtin_amdgcn_mfma_f32_16x16x32_bf16(a, bb[t], acc[t], 0, 0, 0);
    };

    #define LOAD_A(BUF, S) do { if (TRANS == 0) loadA0(BUF, (S)); else loadA1(BUF##2, (S)); } while (0)

    // register-double-buffered K pipeline, hand-unrolled x2 so all indices are static.
    // Schedule per step (matches round-1 passing version):
    //   loadB(next) -> proc(cur) -> loadA(cur slot, s+2)   [A-prefetch AFTER consume]
    LOAD_A(Aa, 0);
    loadB(Ba, 0);
    LOAD_A(Ab, 1);
    #pragma unroll
    for (int s = 0; s < 32; s += 2) {
        // even step s: consume (Aa,Ba)
        loadB(Bb, s + 1);
        proc(Aa, Aa2, Ba);
        if (s + 2 < 32) LOAD_A(Aa, s + 2);
        // odd step s+1: consume (Ab,Bb)
        if (s + 2 < 32) loadB(Ba, s + 2);
        proc(Ab, Ab2, Bb);
        if (s + 3 < 32) LOAD_A(Ab, s + 3);
    }
    #undef LOAD_A

    // cross-wave K reduction in LDS, then store
    __shared__ float buf[16 * NPAD];
    const int row4 = g * 4;
    for (int w4 = 0; w4 < 4; ++w4) {
        if (wave == w4) {
            #pragma unroll
            for (int t = 0; t < NT; ++t) {
                #pragma unroll
                for (int q = 0; q < 4; ++q) {
                    int idx = (row4 + q) * NPAD + t * 16 + r;  // C: col=lane&15, row=(lane>>4)*4+q
                    if (w4 == 0) buf[idx] = acc[t][q];
                    else         buf[idx] += acc[t][q];
                }
            }
        }
        __syncthreads();
    }
    for (int t2 = tid; t2 < 16 * DN; t2 += 256) {
        int row = t2 / DN, col = t2 % DN;
        out[(size_t)(m0 + row) * DN + col] = buf[row * NPAD + col];
    }
}

extern "C" void kernel_launch(void* const* d_in, const int* in_sizes, int n_in,
                              void* d_out, int out_size, void* d_ws, size_t ws_size,
                              hipStream_t stream) {
    const float* adj = (const float*)d_in[0];
    const float* h   = (const float*)d_in[1];
    float* out = (float*)d_out;
    unsigned short* Ht = (unsigned short*)d_ws;  // 160*4096*2 = 1.31 MB scratch

    k_transpose<<<dim3(64, 5), 256, 0, stream>>>(h, Ht);
    // d_out layout: [h_in (L*D) | h_out (L*D)]
    k_gemm<0><<<256, 256, 0, stream>>>(adj, Ht, out + (size_t)LN * DN); // h_out = A  @ h
    k_gemm<1><<<256, 256, 0, stream>>>(adj, Ht, out);                   // h_in  = A.T@ h
}